// Round 1
// baseline (145.144 us; speedup 1.0000x reference)
//
#include <hip/hip_runtime.h>

#define T_ATOMS 60
#define DIM 256
#define NSEG 2048
#define NATOMS 262144
#define NTILES ((NATOMS + T_ATOMS - 1) / T_ATOMS)   /* 4370 */
#define SLOTS (NSEG + NTILES)                        /* 6418 */
#define SEG_PER_BLK 8

// index_list may arrive as int64 (reference dtype) or int32 (JAX x64-off /
// harness convention). Detect on-device: for int64, word[1] is the high half
// of offset 0 (== 0); for int32, word[1] is the first interior offset (>= 1).
__device__ __forceinline__ long long load_off(const void* p, int i, int is64) {
  if (is64) return ((const long long*)p)[i];
  return (long long)((const int*)p)[i];
}

__global__ __launch_bounds__(256, 2)
void pool_tiles(const float* __restrict__ feat,
                const void* __restrict__ offs_raw,
                const float* __restrict__ Wa,
                float* __restrict__ md,
                float* __restrict__ accbuf)
{
  __shared__ float ftile[T_ATOMS * DIM];   // 60 KiB: 2 blocks/CU
  __shared__ float logit_s[T_ATOMS];
  __shared__ float e_s[T_ATOMS];
  __shared__ float red2[2];
  __shared__ int ired[2];

  const int tid  = threadIdx.x;
  const int lane = tid & 63;
  const int wv   = tid >> 6;
  const int u    = blockIdx.x;
  const long long base = (long long)u * T_ATOMS;
  long long rem = (long long)NATOMS - base;
  if (rem <= 0) return;
  const int cnt = rem < T_ATOMS ? (int)rem : T_ATOMS;
  const int is64 = (((const int*)offs_raw)[1] == 0);

  // lane l owns feature dims [4l, 4l+4) for the logit dot
  const float4 wa4 = ((const float4*)Wa)[lane];

  // ---- stage tile into LDS; fold dot-partials in during the copy ----
  const float4* fg = (const float4*)(feat + base * DIM);
  float4* fl = (float4*)ftile;
  const int nf4 = cnt * (DIM / 4);         // multiple of 64 -> wave-uniform trip counts

  float part[15];
  int nmine = 0;
  if (cnt == T_ATOMS) {
    float4 r[15];
#pragma unroll
    for (int k = 0; k < 15; ++k) r[k] = fg[tid + 256 * k];   // 15 loads in flight
#pragma unroll
    for (int k = 0; k < 15; ++k) fl[tid + 256 * k] = r[k];
#pragma unroll
    for (int k = 0; k < 15; ++k)
      part[k] = r[k].x * wa4.x + r[k].y * wa4.y + r[k].z * wa4.z + r[k].w * wa4.w;
    nmine = 15;
  } else {
    for (int i = tid, k = 0; i < nf4; i += 256, ++k) {
      float4 r = fg[i];
      fl[i] = r;
      part[k] = r.x * wa4.x + r.y * wa4.y + r.z * wa4.z + r.w * wa4.w;
      ++nmine;
    }
  }

  // segment range of this tile (overlaps with the loads above)
  if (tid < 2) {
    long long key = (tid == 0) ? base : base + cnt - 1;
    int lo = 0, hi = NSEG;
    while (lo < hi) {                       // max s with off[s] <= key
      int mid = (lo + hi + 1) >> 1;
      if (load_off(offs_raw, mid, is64) <= key) lo = mid; else hi = mid - 1;
    }
    ired[tid] = lo;
  }

  // butterfly-reduce dot partials -> per-atom logits (atom = 4k + wv)
#pragma unroll
  for (int k = 0; k < 15; ++k) {
    if (k < nmine) {
      float p = part[k];
      p += __shfl_xor(p, 32);
      p += __shfl_xor(p, 16);
      p += __shfl_xor(p, 8);
      p += __shfl_xor(p, 4);
      p += __shfl_xor(p, 2);
      p += __shfl_xor(p, 1);
      if (lane == 0) logit_s[4 * k + wv] = p;
    }
  }
  __syncthreads();

  const int s0 = ired[0];
  const int s1 = ired[1];

  for (int s = s0; s <= s1; ++s) {
    long long lo = load_off(offs_raw, s, is64);
    long long hi = load_off(offs_raw, s + 1, is64);
    int la = (int)(lo > base ? lo - base : 0);
    int lb = (int)(hi < base + cnt ? hi - base : (long long)cnt);

    // wave 0: slice max, exp, denom (slice length <= 60 <= 64 lanes)
    if (wv == 0) {
      int a = la + lane;
      float v = (a < lb) ? logit_s[a] : -INFINITY;
      float m = v;
      m = fmaxf(m, __shfl_xor(m, 32));
      m = fmaxf(m, __shfl_xor(m, 16));
      m = fmaxf(m, __shfl_xor(m, 8));
      m = fmaxf(m, __shfl_xor(m, 4));
      m = fmaxf(m, __shfl_xor(m, 2));
      m = fmaxf(m, __shfl_xor(m, 1));
      float e = 0.f;
      if (a < lb) { e = __expf(v - m); e_s[a] = e; }
      float d = e;
      d += __shfl_xor(d, 32);
      d += __shfl_xor(d, 16);
      d += __shfl_xor(d, 8);
      d += __shfl_xor(d, 4);
      d += __shfl_xor(d, 2);
      d += __shfl_xor(d, 1);
      if (lane == 0) { red2[0] = m; red2[1] = d; }
    }
    __syncthreads();

    const float m = red2[0];
    const float d = red2[1];

    // thread owns dim tid: partial weighted sum over this slice
    float acc = 0.f;
    for (int a = la; a < lb; ++a)
      acc = fmaf(e_s[a], ftile[a * DIM + tid], acc);

    const int slot = s + u;                 // injective over intersecting (s,u)
    accbuf[(size_t)slot * DIM + tid] = acc;
    if (tid == 0) { md[2 * slot] = m; md[2 * slot + 1] = d; }
    __syncthreads();                        // red2/e_s reuse by next slice
  }
}

__global__ __launch_bounds__(256)
void merge_project(const float* __restrict__ md,
                   const float* __restrict__ accbuf,
                   const void* __restrict__ offs_raw,
                   const float* __restrict__ Wo,
                   const float* __restrict__ bo,
                   float* __restrict__ out)
{
  __shared__ float pooled[SEG_PER_BLK][DIM];
  const int tid = threadIdx.x;
  const int is64 = (((const int*)offs_raw)[1] == 0);
  const int sbase = blockIdx.x * SEG_PER_BLK;

  for (int j = 0; j < SEG_PER_BLK; ++j) {
    int s = sbase + j;
    long long lo = load_off(offs_raw, s, is64);
    long long hi = load_off(offs_raw, s + 1, is64);
    int u0 = (int)(lo / T_ATOMS);
    int u1 = (int)((hi - 1) / T_ATOMS);
    float M = -INFINITY;
    for (int uu = u0; uu <= u1; ++uu) M = fmaxf(M, md[2 * (s + uu)]);
    float D = 0.f, acc = 0.f;
    for (int uu = u0; uu <= u1; ++uu) {
      int slot = s + uu;
      float sc = __expf(md[2 * slot] - M);
      D += md[2 * slot + 1] * sc;
      acc = fmaf(accbuf[(size_t)slot * DIM + tid], sc, acc);
    }
    pooled[j][tid] = acc / D;
  }
  __syncthreads();

  // out[8 x 256] = pooled @ Wo + bo ; thread owns output dim tid
  float o[SEG_PER_BLK];
#pragma unroll
  for (int j = 0; j < SEG_PER_BLK; ++j) o[j] = 0.f;
  for (int k = 0; k < DIM; ++k) {
    float w = Wo[k * DIM + tid];
#pragma unroll
    for (int j = 0; j < SEG_PER_BLK; ++j)
      o[j] = fmaf(pooled[j][k], w, o[j]);
  }
  const float b = bo[tid];
#pragma unroll
  for (int j = 0; j < SEG_PER_BLK; ++j)
    out[(size_t)(sbase + j) * DIM + tid] = o[j] + b;
}

extern "C" void kernel_launch(void* const* d_in, const int* in_sizes, int n_in,
                              void* d_out, int out_size, void* d_ws, size_t ws_size,
                              hipStream_t stream)
{
  const float* feat = (const float*)d_in[0];
  const void*  offs = d_in[1];
  const float* Wa   = (const float*)d_in[2];
  /* d_in[3] = ba: cancels under softmax shift invariance */
  const float* Wo   = (const float*)d_in[4];
  const float* bo   = (const float*)d_in[5];
  float* out = (float*)d_out;

  float* md     = (float*)d_ws;            // [SLOTS][2]  (m, d)
  float* accbuf = md + 2 * SLOTS;          // [SLOTS][DIM]

  hipLaunchKernelGGL(pool_tiles, dim3(NTILES), dim3(256), 0, stream,
                     feat, offs, Wa, md, accbuf);
  hipLaunchKernelGGL(merge_project, dim3(NSEG / SEG_PER_BLK), dim3(256), 0, stream,
                     md, accbuf, offs, Wo, bo, out);
}

// Round 2
// 114.811 us; speedup vs baseline: 1.2642x; 1.2642x over previous
//
#include <hip/hip_runtime.h>

#define T_ATOMS 60
#define DIM 256
#define NSEG 2048
#define NATOMS 262144
#define NTILES ((NATOMS + T_ATOMS - 1) / T_ATOMS)   /* 4370 */
#define SLOTS (NSEG + NTILES)                        /* 6418 */
#define SEG_PER_BLK 8

// index_list may arrive as int64 (reference dtype) or int32. Detect on-device:
// for int64, word[1] is the high half of offset 0 (== 0); for int32, word[1]
// is the first interior offset (>= 1).
__device__ __forceinline__ long long load_off(const void* p, int i, int is64) {
  if (is64) return ((const long long*)p)[i];
  return (long long)((const int*)p)[i];
}

// Tile resident in REGISTERS (15 x float4/thread): thread (wv,lane) holds
// dims [4*lane,4*lane+4) of atoms {4k+wv}. No 60KiB LDS tile, no ds_read
// latency chain in the weighted sum -> 4 blocks/CU instead of 2.
__global__ __launch_bounds__(256, 4)
void pool_tiles(const float* __restrict__ feat,
                const void* __restrict__ offs_raw,
                const float* __restrict__ Wa,
                float* __restrict__ md,
                float* __restrict__ accbuf)
{
  __shared__ float logit_s[T_ATOMS];
  __shared__ float e_s[T_ATOMS];
  __shared__ float4 red4[4][64];   // cross-wave reduction buffer (4 KiB)
  __shared__ float red2[2];
  __shared__ int ired[2];

  const int tid  = threadIdx.x;
  const int lane = tid & 63;
  const int wv   = tid >> 6;
  const int u    = blockIdx.x;
  const long long base = (long long)u * T_ATOMS;
  long long rem = (long long)NATOMS - base;
  const int cnt = rem < T_ATOMS ? (int)rem : T_ATOMS;
  const int is64 = (((const int*)offs_raw)[1] == 0);

  const float4 wa4 = ((const float4*)Wa)[lane];
  const float4* fg = (const float4*)(feat + base * DIM);

  // ---- issue all tile loads into registers (15 in flight/thread) ----
  float4 r[15];
  if (cnt == T_ATOMS) {
#pragma unroll
    for (int k = 0; k < 15; ++k) r[k] = fg[tid + 256 * k];
  } else {
    const int nf4 = cnt * (DIM / 4);
#pragma unroll
    for (int k = 0; k < 15; ++k) {
      int i = tid + 256 * k;
      if (i < nf4) r[k] = fg[i];
    }
  }

  // ---- parallel segment-range scan (overlaps the loads in flight) ----
  // max 8 straddle checks/thread, all independent: one L2 round-trip.
  {
    const long long key0 = base, key1 = base + cnt - 1;
#pragma unroll
    for (int j = 0; j < NSEG / 256; ++j) {
      int s = tid + 256 * j;
      long long a = load_off(offs_raw, s, is64);
      long long b = load_off(offs_raw, s + 1, is64);
      if (a <= key0 && key0 < b) ired[0] = s;
      if (a <= key1 && key1 < b) ired[1] = s;
    }
  }

  // ---- logits: butterfly-reduce each atom's dot across the 64 lanes ----
#pragma unroll
  for (int k = 0; k < 15; ++k) {
    int atom = 4 * k + wv;            // wave-uniform guard: shuffles safe
    if (atom < cnt) {
      float p = r[k].x * wa4.x + r[k].y * wa4.y + r[k].z * wa4.z + r[k].w * wa4.w;
      p += __shfl_xor(p, 32);
      p += __shfl_xor(p, 16);
      p += __shfl_xor(p, 8);
      p += __shfl_xor(p, 4);
      p += __shfl_xor(p, 2);
      p += __shfl_xor(p, 1);
      if (lane == 0) logit_s[atom] = p;
    }
  }
  __syncthreads();

  const int s0 = ired[0];
  const int s1 = ired[1];

  for (int s = s0; s <= s1; ++s) {
    long long lo = load_off(offs_raw, s, is64);
    long long hi = load_off(offs_raw, s + 1, is64);
    const int la = (int)(lo > base ? lo - base : 0);
    const int lb = (int)(hi < base + cnt ? hi - base : (long long)cnt);

    // wave 0: slice max, exp, denom (slice length <= 60 <= 64 lanes)
    if (wv == 0) {
      int a = la + lane;
      float v = (a < lb) ? logit_s[a] : -INFINITY;
      float m = v;
      m = fmaxf(m, __shfl_xor(m, 32));
      m = fmaxf(m, __shfl_xor(m, 16));
      m = fmaxf(m, __shfl_xor(m, 8));
      m = fmaxf(m, __shfl_xor(m, 4));
      m = fmaxf(m, __shfl_xor(m, 2));
      m = fmaxf(m, __shfl_xor(m, 1));
      float e = 0.f;
      if (a < lb) { e = __expf(v - m); e_s[a] = e; }
      float d = e;
      d += __shfl_xor(d, 32);
      d += __shfl_xor(d, 16);
      d += __shfl_xor(d, 8);
      d += __shfl_xor(d, 4);
      d += __shfl_xor(d, 2);
      d += __shfl_xor(d, 1);
      if (lane == 0) { red2[0] = m; red2[1] = d; }
    }
    __syncthreads();

    // in-register weighted partial sum: 15 independent FMAs, e broadcast
    float4 acc = make_float4(0.f, 0.f, 0.f, 0.f);
#pragma unroll
    for (int k = 0; k < 15; ++k) {
      int atom = 4 * k + wv;
      if (atom >= la && atom < lb) {
        float e = e_s[atom];          // wave-uniform addr -> LDS broadcast
        acc.x = fmaf(e, r[k].x, acc.x);
        acc.y = fmaf(e, r[k].y, acc.y);
        acc.z = fmaf(e, r[k].z, acc.z);
        acc.w = fmaf(e, r[k].w, acc.w);
      }
    }
    red4[wv][lane] = acc;
    __syncthreads();

    if (wv == 0) {
      float4 a0 = red4[0][lane], a1 = red4[1][lane],
             a2 = red4[2][lane], a3 = red4[3][lane];
      float4 t;
      t.x = (a0.x + a1.x) + (a2.x + a3.x);
      t.y = (a0.y + a1.y) + (a2.y + a3.y);
      t.z = (a0.z + a1.z) + (a2.z + a3.z);
      t.w = (a0.w + a1.w) + (a2.w + a3.w);
      const int slot = s + u;         // injective over intersecting (s,u)
      ((float4*)(accbuf + (size_t)slot * DIM))[lane] = t;
      if (lane == 0) { md[2 * slot] = red2[0]; md[2 * slot + 1] = red2[1]; }
    }
    __syncthreads();                  // red2/e_s/red4 reuse by next slice
  }
}

__global__ __launch_bounds__(256)
void merge_project(const float* __restrict__ md,
                   const float* __restrict__ accbuf,
                   const void* __restrict__ offs_raw,
                   const float* __restrict__ Wo,
                   const float* __restrict__ bo,
                   float* __restrict__ out)
{
  __shared__ float pooled[SEG_PER_BLK][DIM];
  const int tid = threadIdx.x;
  const int is64 = (((const int*)offs_raw)[1] == 0);
  const int sbase = blockIdx.x * SEG_PER_BLK;

  for (int j = 0; j < SEG_PER_BLK; ++j) {
    int s = sbase + j;
    long long lo = load_off(offs_raw, s, is64);
    long long hi = load_off(offs_raw, s + 1, is64);
    int u0 = (int)(lo / T_ATOMS);
    int u1 = (int)((hi - 1) / T_ATOMS);
    float M = -INFINITY;
    for (int uu = u0; uu <= u1; ++uu) M = fmaxf(M, md[2 * (s + uu)]);
    float D = 0.f, acc = 0.f;
    for (int uu = u0; uu <= u1; ++uu) {
      int slot = s + uu;
      float sc = __expf(md[2 * slot] - M);
      D += md[2 * slot + 1] * sc;
      acc = fmaf(accbuf[(size_t)slot * DIM + tid], sc, acc);
    }
    pooled[j][tid] = acc / D;
  }
  __syncthreads();

  // out[8 x 256] = pooled @ Wo + bo ; thread owns output dim tid
  float o[SEG_PER_BLK];
#pragma unroll
  for (int j = 0; j < SEG_PER_BLK; ++j) o[j] = 0.f;
  for (int k = 0; k < DIM; ++k) {
    float w = Wo[k * DIM + tid];
#pragma unroll
    for (int j = 0; j < SEG_PER_BLK; ++j)
      o[j] = fmaf(pooled[j][k], w, o[j]);
  }
  const float b = bo[tid];
#pragma unroll
  for (int j = 0; j < SEG_PER_BLK; ++j)
    out[(size_t)(sbase + j) * DIM + tid] = o[j] + b;
}

extern "C" void kernel_launch(void* const* d_in, const int* in_sizes, int n_in,
                              void* d_out, int out_size, void* d_ws, size_t ws_size,
                              hipStream_t stream)
{
  const float* feat = (const float*)d_in[0];
  const void*  offs = d_in[1];
  const float* Wa   = (const float*)d_in[2];
  /* d_in[3] = ba: cancels under softmax shift invariance */
  const float* Wo   = (const float*)d_in[4];
  const float* bo   = (const float*)d_in[5];
  float* out = (float*)d_out;

  float* md     = (float*)d_ws;            // [SLOTS][2]  (m, d)
  float* accbuf = md + 2 * SLOTS;          // [SLOTS][DIM]

  hipLaunchKernelGGL(pool_tiles, dim3(NTILES), dim3(256), 0, stream,
                     feat, offs, Wa, md, accbuf);
  hipLaunchKernelGGL(merge_project, dim3(NSEG / SEG_PER_BLK), dim3(256), 0, stream,
                     md, accbuf, offs, Wo, bo, out);
}

// Round 3
// 90.608 us; speedup vs baseline: 1.6019x; 1.2671x over previous
//
#include <hip/hip_runtime.h>

#define DIM 256
#define NSEG 2048
#define NATOMS 262144
#define TA 16                        /* atoms per wave-tile */
#define NTILES (NATOMS / TA)         /* 16384, exact */
#define SLOTS (NSEG + NTILES)        /* 18432 */

// index_list may arrive as int64 (reference dtype) or int32. Detect on-device:
// for int64, word[1] is the high half of offset 0 (== 0); for int32, word[1]
// is the first interior offset (>= 1).
__device__ __forceinline__ long long load_off(const void* p, int i, int is64) {
  if (is64) return ((const long long*)p)[i];
  return (long long)((const int*)p)[i];
}

// s0tab[u] = segment containing atom TA*u, for u in [0, NTILES].
// One thread per segment scatter-writes its tile range (contiguous coverage).
__global__ void seg_of_tile(const void* __restrict__ offs_raw,
                            int* __restrict__ s0tab)
{
  int s = blockIdx.x * blockDim.x + threadIdx.x;
  if (s >= NSEG) return;
  const int is64 = (((const int*)offs_raw)[1] == 0);
  int lo = (int)load_off(offs_raw, s, is64);
  int hi = (int)load_off(offs_raw, s + 1, is64);
  int u0 = (lo + TA - 1) / TA;
  int u1 = (hi + TA - 1) / TA - 1;
  for (int u = u0; u <= u1; ++u) s0tab[u] = s;
  if (s == NSEG - 1) s0tab[NTILES] = NSEG - 1;
}

// Wave-autonomous pooling: zero LDS, zero barriers. Lane l holds dims
// [4l,4l+4) of atoms 16u..16u+15 in registers; butterfly leaves each atom's
// logit in ALL lanes, so softmax + weighted sum are pure per-lane math.
__global__ __launch_bounds__(256, 4)
void pool_waves(const float* __restrict__ feat,
                const void* __restrict__ offs_raw,
                const float* __restrict__ Wa,
                const int* __restrict__ s0tab,
                float* __restrict__ md,
                float* __restrict__ accbuf)
{
  const int lane = threadIdx.x & 63;
  const int wv   = threadIdx.x >> 6;
  const int u    = blockIdx.x * 4 + wv;
  const int base = u * TA;
  const int is64 = (((const int*)offs_raw)[1] == 0);

  const float4 wa4 = ((const float4*)Wa)[lane];
  const float4* fg = (const float4*)feat + (size_t)base * (DIM / 4);

  // 16 coalesced 1-KiB row loads, all independent and in flight at once
  float4 r[TA];
#pragma unroll
  for (int k = 0; k < TA; ++k) r[k] = fg[(size_t)k * 64 + lane];

  // segment range of this tile from the precomputed table (L2-hot)
  const int s0  = s0tab[u];
  const int s1n = s0tab[u + 1];
  const int e1  = (int)load_off(offs_raw, s1n, is64);
  const int s1  = s1n - (e1 == base + TA ? 1 : 0);

  // per-atom logits, result broadcast to all 64 lanes
  float lg[TA];
#pragma unroll
  for (int k = 0; k < TA; ++k) {
    float p = r[k].x * wa4.x + r[k].y * wa4.y + r[k].z * wa4.z + r[k].w * wa4.w;
    p += __shfl_xor(p, 32);
    p += __shfl_xor(p, 16);
    p += __shfl_xor(p, 8);
    p += __shfl_xor(p, 4);
    p += __shfl_xor(p, 2);
    p += __shfl_xor(p, 1);
    lg[k] = p;
  }

  if (s0 == s1) {
    // fast path (~87%): whole tile inside one segment, no off[] loads
    float m = lg[0];
#pragma unroll
    for (int k = 1; k < TA; ++k) m = fmaxf(m, lg[k]);
    float d = 0.f;
    float4 acc = make_float4(0.f, 0.f, 0.f, 0.f);
#pragma unroll
    for (int k = 0; k < TA; ++k) {
      float e = __expf(lg[k] - m);
      d += e;
      acc.x = fmaf(e, r[k].x, acc.x);
      acc.y = fmaf(e, r[k].y, acc.y);
      acc.z = fmaf(e, r[k].z, acc.z);
      acc.w = fmaf(e, r[k].w, acc.w);
    }
    const int slot = s0 + u;           // injective over intersecting (s,u)
    ((float4*)(accbuf + (size_t)slot * DIM))[lane] = acc;
    if (lane == 0) { md[2 * slot] = m; md[2 * slot + 1] = d; }
  } else {
    for (int s = s0; s <= s1; ++s) {   // wave-uniform loop
      int lo = (int)load_off(offs_raw, s, is64);
      int hi = (int)load_off(offs_raw, s + 1, is64);
      int la = lo - base; la = la > 0 ? la : 0;
      int lb = hi - base; lb = lb < TA ? lb : TA;
      float m = -INFINITY;
#pragma unroll
      for (int k = 0; k < TA; ++k)
        if (k >= la && k < lb) m = fmaxf(m, lg[k]);
      float d = 0.f;
      float4 acc = make_float4(0.f, 0.f, 0.f, 0.f);
#pragma unroll
      for (int k = 0; k < TA; ++k) {
        bool v = (k >= la && k < lb);
        float e = v ? __expf(lg[k] - m) : 0.f;
        d += e;
        acc.x = fmaf(e, r[k].x, acc.x);
        acc.y = fmaf(e, r[k].y, acc.y);
        acc.z = fmaf(e, r[k].z, acc.z);
        acc.w = fmaf(e, r[k].w, acc.w);
      }
      const int slot = s + u;
      ((float4*)(accbuf + (size_t)slot * DIM))[lane] = acc;
      if (lane == 0) { md[2 * slot] = m; md[2 * slot + 1] = d; }
    }
  }
}

// wave-per-segment merge (flash-style rescale) + block projection GEMM
__global__ __launch_bounds__(256, 2)
void merge_project(const float* __restrict__ md,
                   const float* __restrict__ accbuf,
                   const void* __restrict__ offs_raw,
                   const float* __restrict__ Wo,
                   const float* __restrict__ bo,
                   float* __restrict__ out)
{
  __shared__ float pooled[4][DIM];
  const int tid  = threadIdx.x;
  const int lane = tid & 63;
  const int wv   = tid >> 6;
  const int is64 = (((const int*)offs_raw)[1] == 0);
  const int s    = blockIdx.x * 4 + wv;

  {
    int lo = (int)load_off(offs_raw, s, is64);
    int hi = (int)load_off(offs_raw, s + 1, is64);
    int u0 = lo / TA;
    int u1 = (hi - 1) / TA;
    float M = -INFINITY;
    for (int uu = u0; uu <= u1; ++uu)
      M = fmaxf(M, md[2 * (s + uu)]);
    float D = 0.f;
    float4 acc = make_float4(0.f, 0.f, 0.f, 0.f);
    for (int uu = u0; uu <= u1; ++uu) {
      int slot = s + uu;
      float sc = __expf(md[2 * slot] - M);
      D += md[2 * slot + 1] * sc;
      float4 a = ((const float4*)(accbuf + (size_t)slot * DIM))[lane];
      acc.x = fmaf(a.x, sc, acc.x);
      acc.y = fmaf(a.y, sc, acc.y);
      acc.z = fmaf(a.z, sc, acc.z);
      acc.w = fmaf(a.w, sc, acc.w);
    }
    float inv = 1.f / D;
    ((float4*)pooled[wv])[lane] =
        make_float4(acc.x * inv, acc.y * inv, acc.z * inv, acc.w * inv);
  }
  __syncthreads();

  // out[4 x 256] = pooled @ Wo + bo ; thread owns output dim tid
  float o0 = 0.f, o1 = 0.f, o2 = 0.f, o3 = 0.f;
  for (int k = 0; k < DIM; ++k) {
    float w = Wo[k * DIM + tid];           // coalesced; Wo is L2-resident
    o0 = fmaf(pooled[0][k], w, o0);        // LDS broadcast reads
    o1 = fmaf(pooled[1][k], w, o1);
    o2 = fmaf(pooled[2][k], w, o2);
    o3 = fmaf(pooled[3][k], w, o3);
  }
  const float b = bo[tid];
  const int sb = blockIdx.x * 4;
  out[(size_t)(sb + 0) * DIM + tid] = o0 + b;
  out[(size_t)(sb + 1) * DIM + tid] = o1 + b;
  out[(size_t)(sb + 2) * DIM + tid] = o2 + b;
  out[(size_t)(sb + 3) * DIM + tid] = o3 + b;
}

extern "C" void kernel_launch(void* const* d_in, const int* in_sizes, int n_in,
                              void* d_out, int out_size, void* d_ws, size_t ws_size,
                              hipStream_t stream)
{
  const float* feat = (const float*)d_in[0];
  const void*  offs = d_in[1];
  const float* Wa   = (const float*)d_in[2];
  /* d_in[3] = ba: cancels under softmax shift invariance */
  const float* Wo   = (const float*)d_in[4];
  const float* bo   = (const float*)d_in[5];
  float* out = (float*)d_out;

  float* md     = (float*)d_ws;                    // [SLOTS][2]
  float* accbuf = md + 2 * SLOTS;                  // [SLOTS][DIM]
  int*   s0tab  = (int*)(accbuf + (size_t)SLOTS * DIM);  // [NTILES+1]

  hipLaunchKernelGGL(seg_of_tile, dim3((NSEG + 255) / 256), dim3(256), 0, stream,
                     offs, s0tab);
  hipLaunchKernelGGL(pool_waves, dim3(NTILES / 4), dim3(256), 0, stream,
                     feat, offs, Wa, s0tab, md, accbuf);
  hipLaunchKernelGGL(merge_project, dim3(NSEG / 4), dim3(256), 0, stream,
                     md, accbuf, offs, Wo, bo, out);
}

// Round 4
// 79.858 us; speedup vs baseline: 1.8175x; 1.1346x over previous
//
#include <hip/hip_runtime.h>

#define DIM 256
#define NSEG 2048
#define NATOMS 262144
#define TA 8                         /* atoms per wave-tile */
#define NTILES (NATOMS / TA)         /* 32768, exact */
#define SLOTS (NSEG + NTILES)        /* 34816 */

// index_list may arrive as int64 (reference dtype) or int32. Detect on-device:
// for int64, word[1] is the high half of offset 0 (== 0); for int32, word[1]
// is the first interior offset (>= 1).
__device__ __forceinline__ long long load_off(const void* p, int i, int is64) {
  if (is64) return ((const long long*)p)[i];
  return (long long)((const int*)p)[i];
}

// s0tab[u] = segment containing atom TA*u, for u in [0, NTILES].
// One thread per segment scatter-writes its tile range (contiguous coverage).
__global__ void seg_of_tile(const void* __restrict__ offs_raw,
                            int* __restrict__ s0tab)
{
  int s = blockIdx.x * blockDim.x + threadIdx.x;
  if (s >= NSEG) return;
  const int is64 = (((const int*)offs_raw)[1] == 0);
  int lo = (int)load_off(offs_raw, s, is64);
  int hi = (int)load_off(offs_raw, s + 1, is64);
  int u0 = (lo + TA - 1) / TA;
  int u1 = (hi + TA - 1) / TA - 1;
  for (int u = u0; u <= u1; ++u) s0tab[u] = s;
  if (s == NSEG - 1) s0tab[NTILES] = NSEG - 1;
}

// Wave-autonomous pooling: zero LDS, zero barriers, and (the R4 point)
// zero register spills: r[8]=32 VGPR, total ~80 << 128 cap at 4 blk/CU.
__global__ __launch_bounds__(256, 4)
void pool_waves(const float* __restrict__ feat,
                const void* __restrict__ offs_raw,
                const float* __restrict__ Wa,
                const int* __restrict__ s0tab,
                float* __restrict__ md,
                float* __restrict__ accbuf)
{
  const int lane = threadIdx.x & 63;
  const int wv   = threadIdx.x >> 6;
  const int u    = blockIdx.x * 4 + wv;
  const int base = u * TA;
  const int is64 = (((const int*)offs_raw)[1] == 0);

  const float4 wa4 = ((const float4*)Wa)[lane];
  const float4* fg = (const float4*)feat + (size_t)base * (DIM / 4);

  // 8 coalesced 1-KiB row loads, all independent and in flight at once
  float4 r[TA];
#pragma unroll
  for (int k = 0; k < TA; ++k) r[k] = fg[(size_t)k * 64 + lane];

  // segment range of this tile from the precomputed table (L2-hot)
  const int s0  = s0tab[u];
  const int s1n = s0tab[u + 1];
  const int e1  = (int)load_off(offs_raw, s1n, is64);
  const int s1  = s1n - (e1 == base + TA ? 1 : 0);

  // per-atom logits, result broadcast to all 64 lanes
  float lg[TA];
#pragma unroll
  for (int k = 0; k < TA; ++k) {
    float p = r[k].x * wa4.x + r[k].y * wa4.y + r[k].z * wa4.z + r[k].w * wa4.w;
    p += __shfl_xor(p, 32);
    p += __shfl_xor(p, 16);
    p += __shfl_xor(p, 8);
    p += __shfl_xor(p, 4);
    p += __shfl_xor(p, 2);
    p += __shfl_xor(p, 1);
    lg[k] = p;
  }

  if (s0 == s1) {
    // fast path (~94%): whole tile inside one segment
    float m = lg[0];
#pragma unroll
    for (int k = 1; k < TA; ++k) m = fmaxf(m, lg[k]);
    float d = 0.f;
    float4 acc = make_float4(0.f, 0.f, 0.f, 0.f);
#pragma unroll
    for (int k = 0; k < TA; ++k) {
      float e = __expf(lg[k] - m);
      d += e;
      acc.x = fmaf(e, r[k].x, acc.x);
      acc.y = fmaf(e, r[k].y, acc.y);
      acc.z = fmaf(e, r[k].z, acc.z);
      acc.w = fmaf(e, r[k].w, acc.w);
    }
    const int slot = s0 + u;           // injective over intersecting (s,u)
    ((float4*)(accbuf + (size_t)slot * DIM))[lane] = acc;
    if (lane == 0) { md[2 * slot] = m; md[2 * slot + 1] = d; }
  } else {
    for (int s = s0; s <= s1; ++s) {   // wave-uniform loop
      int lo = (int)load_off(offs_raw, s, is64);
      int hi = (int)load_off(offs_raw, s + 1, is64);
      int la = lo - base; la = la > 0 ? la : 0;
      int lb = hi - base; lb = lb < TA ? lb : TA;
      float m = -INFINITY;
#pragma unroll
      for (int k = 0; k < TA; ++k)
        if (k >= la && k < lb) m = fmaxf(m, lg[k]);
      float d = 0.f;
      float4 acc = make_float4(0.f, 0.f, 0.f, 0.f);
#pragma unroll
      for (int k = 0; k < TA; ++k) {
        bool v = (k >= la && k < lb);
        float e = v ? __expf(lg[k] - m) : 0.f;
        d += e;
        acc.x = fmaf(e, r[k].x, acc.x);
        acc.y = fmaf(e, r[k].y, acc.y);
        acc.z = fmaf(e, r[k].z, acc.z);
        acc.w = fmaf(e, r[k].w, acc.w);
      }
      const int slot = s + u;
      ((float4*)(accbuf + (size_t)slot * DIM))[lane] = acc;
      if (lane == 0) { md[2 * slot] = m; md[2 * slot + 1] = d; }
    }
  }
}

// wave-per-segment flash-merge, chunk-of-64: each LANE owns one partial slot
// (parallel max/denominator via butterflies), then a 4-unrolled accumulate
// over the chunk's slots with scales broadcast from LDS. Bounds the tail for
// the longest segment (~165 slots -> 3 chunks) instead of 165 serial iters.
__global__ __launch_bounds__(256, 2)
void merge_project(const float* __restrict__ md,
                   const float* __restrict__ accbuf,
                   const void* __restrict__ offs_raw,
                   const float* __restrict__ Wo,
                   const float* __restrict__ bo,
                   float* __restrict__ out)
{
  __shared__ float pooled[4][DIM];
  __shared__ float sc_s[4][64];
  const int tid  = threadIdx.x;
  const int lane = tid & 63;
  const int wv   = tid >> 6;
  const int is64 = (((const int*)offs_raw)[1] == 0);
  const int s    = blockIdx.x * 4 + wv;

  {
    const int lo = (int)load_off(offs_raw, s, is64);
    const int hi = (int)load_off(offs_raw, s + 1, is64);
    const int u0 = lo / TA;
    const int u1 = (hi - 1) / TA;
    const int n  = u1 - u0 + 1;

    float M = -INFINITY, D = 0.f;
    float4 acc = make_float4(0.f, 0.f, 0.f, 0.f);

    for (int c0 = 0; c0 < n; c0 += 64) {
      const int j = c0 + lane;
      const bool v = (j < n);
      const int slot = s + u0 + j;
      float mj = v ? md[2 * slot] : -INFINITY;
      float dj = v ? md[2 * slot + 1] : 0.f;

      float Mc = mj;                     // chunk max -> all lanes
      Mc = fmaxf(Mc, __shfl_xor(Mc, 32));
      Mc = fmaxf(Mc, __shfl_xor(Mc, 16));
      Mc = fmaxf(Mc, __shfl_xor(Mc, 8));
      Mc = fmaxf(Mc, __shfl_xor(Mc, 4));
      Mc = fmaxf(Mc, __shfl_xor(Mc, 2));
      Mc = fmaxf(Mc, __shfl_xor(Mc, 1));
      const float Mn = fmaxf(M, Mc);
      const float rs = (c0 == 0) ? 0.f : __expf(M - Mn);  // avoid -inf - -inf
      const float scj = __expf(mj - Mn);                  // 0 for invalid lanes

      float t = dj * scj;                // chunk denom -> all lanes
      t += __shfl_xor(t, 32);
      t += __shfl_xor(t, 16);
      t += __shfl_xor(t, 8);
      t += __shfl_xor(t, 4);
      t += __shfl_xor(t, 2);
      t += __shfl_xor(t, 1);
      D = D * rs + t;

      sc_s[wv][lane] = scj;              // wave-coherent LDS stage

      acc.x *= rs; acc.y *= rs; acc.z *= rs; acc.w *= rs;

      const int cn = (n - c0) < 64 ? (n - c0) : 64;
      const float4* ab = (const float4*)(accbuf + (size_t)(s + u0 + c0) * DIM);
      int jj = 0;
      for (; jj + 4 <= cn; jj += 4) {    // 4 independent 1-KiB reads in flight
        float4 a0 = ab[(size_t)(jj + 0) * 64 + lane];
        float4 a1 = ab[(size_t)(jj + 1) * 64 + lane];
        float4 a2 = ab[(size_t)(jj + 2) * 64 + lane];
        float4 a3 = ab[(size_t)(jj + 3) * 64 + lane];
        float s0 = sc_s[wv][jj + 0], s1 = sc_s[wv][jj + 1];
        float s2 = sc_s[wv][jj + 2], s3 = sc_s[wv][jj + 3];
        acc.x = fmaf(s0, a0.x, fmaf(s1, a1.x, fmaf(s2, a2.x, fmaf(s3, a3.x, acc.x))));
        acc.y = fmaf(s0, a0.y, fmaf(s1, a1.y, fmaf(s2, a2.y, fmaf(s3, a3.y, acc.y))));
        acc.z = fmaf(s0, a0.z, fmaf(s1, a1.z, fmaf(s2, a2.z, fmaf(s3, a3.z, acc.z))));
        acc.w = fmaf(s0, a0.w, fmaf(s1, a1.w, fmaf(s2, a2.w, fmaf(s3, a3.w, acc.w))));
      }
      for (; jj < cn; ++jj) {
        float4 a0 = ab[(size_t)jj * 64 + lane];
        float s0 = sc_s[wv][jj];
        acc.x = fmaf(s0, a0.x, acc.x);
        acc.y = fmaf(s0, a0.y, acc.y);
        acc.z = fmaf(s0, a0.z, acc.z);
        acc.w = fmaf(s0, a0.w, acc.w);
      }
      M = Mn;
    }

    const float inv = 1.f / D;
    ((float4*)pooled[wv])[lane] =
        make_float4(acc.x * inv, acc.y * inv, acc.z * inv, acc.w * inv);
  }
  __syncthreads();

  // out[4 x 256] = pooled @ Wo + bo ; thread owns output dim tid
  float o0 = 0.f, o1 = 0.f, o2 = 0.f, o3 = 0.f;
  for (int k = 0; k < DIM; ++k) {
    float w = Wo[k * DIM + tid];           // coalesced; Wo is L2-resident
    o0 = fmaf(pooled[0][k], w, o0);        // LDS broadcast reads
    o1 = fmaf(pooled[1][k], w, o1);
    o2 = fmaf(pooled[2][k], w, o2);
    o3 = fmaf(pooled[3][k], w, o3);
  }
  const float b = bo[tid];
  const int sb = blockIdx.x * 4;
  out[(size_t)(sb + 0) * DIM + tid] = o0 + b;
  out[(size_t)(sb + 1) * DIM + tid] = o1 + b;
  out[(size_t)(sb + 2) * DIM + tid] = o2 + b;
  out[(size_t)(sb + 3) * DIM + tid] = o3 + b;
}

extern "C" void kernel_launch(void* const* d_in, const int* in_sizes, int n_in,
                              void* d_out, int out_size, void* d_ws, size_t ws_size,
                              hipStream_t stream)
{
  const float* feat = (const float*)d_in[0];
  const void*  offs = d_in[1];
  const float* Wa   = (const float*)d_in[2];
  /* d_in[3] = ba: cancels under softmax shift invariance */
  const float* Wo   = (const float*)d_in[4];
  const float* bo   = (const float*)d_in[5];
  float* out = (float*)d_out;

  float* md     = (float*)d_ws;                    // [SLOTS][2]
  float* accbuf = md + 2 * SLOTS;                  // [SLOTS][DIM]
  int*   s0tab  = (int*)(accbuf + (size_t)SLOTS * DIM);  // [NTILES+1]

  hipLaunchKernelGGL(seg_of_tile, dim3((NSEG + 255) / 256), dim3(256), 0, stream,
                     offs, s0tab);
  hipLaunchKernelGGL(pool_waves, dim3(NTILES / 4), dim3(256), 0, stream,
                     feat, offs, Wa, s0tab, md, accbuf);
  hipLaunchKernelGGL(merge_project, dim3(NSEG / 4), dim3(256), 0, stream,
                     md, accbuf, offs, Wo, bo, out);
}